// Round 1
// baseline (537.273 us; speedup 1.0000x reference)
//
#include <hip/hip_runtime.h>
#include <hip/hip_bf16.h>

#define Bv 2
#define Tv 2048
#define Cv 1024
#define Hv 16
#define HSv 64
#define HIDv 2730
#define HIDP 2816
#define Mv 4096

using bf16x8 = __attribute__((ext_vector_type(8))) __bf16;
using f32x4  = __attribute__((ext_vector_type(4))) float;

// ---------------- cast / pad kernels ----------------
__global__ void k_cast(const float* __restrict__ src, __bf16* __restrict__ dst,
                       long n_src, long n_total) {
    long i = (long)blockIdx.x * blockDim.x + threadIdx.x;
    long stride = (long)gridDim.x * blockDim.x;
    for (; i < n_total; i += stride)
        dst[i] = (i < n_src) ? (__bf16)src[i] : (__bf16)0.0f;
}

__global__ void k_cast_padcols(const float* __restrict__ src, __bf16* __restrict__ dst,
                               int rows, int sc, int dc) {
    long total = (long)rows * dc;
    long i = (long)blockIdx.x * blockDim.x + threadIdx.x;
    long stride = (long)gridDim.x * blockDim.x;
    for (; i < total; i += stride) {
        int r = (int)(i / dc), c = (int)(i % dc);
        dst[i] = (c < sc) ? (__bf16)src[(long)r * sc + c] : (__bf16)0.0f;
    }
}

// ---------------- rmsnorm ----------------
__global__ __launch_bounds__(256) void k_rmsnorm(const float* __restrict__ x,
                                                 const float* __restrict__ w,
                                                 float* __restrict__ yf,
                                                 __bf16* __restrict__ yh) {
    int row = blockIdx.x;
    const float4* xr = (const float4*)(x + (size_t)row * Cv);
    float4 a = xr[threadIdx.x];
    float ss = a.x * a.x + a.y * a.y + a.z * a.z + a.w * a.w;
#pragma unroll
    for (int m = 1; m < 64; m <<= 1) ss += __shfl_xor(ss, m);
    __shared__ float red[4];
    if ((threadIdx.x & 63) == 0) red[threadIdx.x >> 6] = ss;
    __syncthreads();
    float tot = red[0] + red[1] + red[2] + red[3];
    float sc = rsqrtf(tot * (1.0f / Cv) + 1e-6f);
    float4 wv = ((const float4*)w)[threadIdx.x];
    float4 o;
    o.x = a.x * sc * wv.x; o.y = a.y * sc * wv.y;
    o.z = a.z * sc * wv.z; o.w = a.w * sc * wv.w;
    ((float4*)(yf + (size_t)row * Cv))[threadIdx.x] = o;
    __bf16* yp = yh + (size_t)row * Cv + threadIdx.x * 4;
    yp[0] = (__bf16)o.x; yp[1] = (__bf16)o.y; yp[2] = (__bf16)o.z; yp[3] = (__bf16)o.w;
}

// ---------------- RoPE (in-place on Q and K, bf16 [M, C]) ----------------
__global__ void k_rope(__bf16* __restrict__ Q, __bf16* __restrict__ Kt,
                       const float* __restrict__ cosT, const float* __restrict__ sinT) {
    long total = (long)Mv * 512;  // 512 (h,i) pairs per row
    long i = (long)blockIdx.x * blockDim.x + threadIdx.x;
    if (i >= total) return;
    int row = (int)(i >> 9);
    int p = (int)(i & 511);
    int h = p >> 5, ii = p & 31;
    int t = row & (Tv - 1);
    float c = cosT[t * 32 + ii], s = sinT[t * 32 + ii];
    long idx = (long)row * Cv + h * 64 + 2 * ii;
    float x0 = (float)Q[idx], x1 = (float)Q[idx + 1];
    Q[idx]     = (__bf16)(x0 * c - x1 * s);
    Q[idx + 1] = (__bf16)(x0 * s + x1 * c);
    float y0 = (float)Kt[idx], y1 = (float)Kt[idx + 1];
    Kt[idx]     = (__bf16)(y0 * c - y1 * s);
    Kt[idx + 1] = (__bf16)(y0 * s + y1 * c);
}

// ---------------- GEMM: C[M,N] = A[M,K] @ B[N,K]^T  (bf16 in, f32 acc) ----------------
// EPI 0: write bf16 outH
// EPI 1: outF = acc (+bias[col]) (+resid[idx])     (f32)
// EPI 3: outH = swish_bug(h1[idx]+b1[col]) * (acc + b2[col])  (bf16), cols>=nbias -> bias 0
template <int EPI>
__global__ __launch_bounds__(256) void k_gemm(
    const __bf16* __restrict__ A, const __bf16* __restrict__ Bm,
    int M, int N, int K,
    float* __restrict__ outF, __bf16* __restrict__ outH,
    const float* __restrict__ bias, int nbias,
    const float* __restrict__ resid,
    const float* __restrict__ h1, const float* __restrict__ bias2) {
    __shared__ __align__(16) __bf16 As[128][72];
    __shared__ __align__(16) __bf16 Bs[128][72];
    int tid = threadIdx.x;
    int lane = tid & 63, wave = tid >> 6;
    int wr = wave >> 1, wc = wave & 1;
    int m0 = blockIdx.y * 128, n0 = blockIdx.x * 128;
    f32x4 acc[4][4] = {};
    int ar = tid >> 3;
    int ac = (tid & 7) * 8;
    int fr = lane & 15, fo = (lane >> 4) * 8;
    for (int k0 = 0; k0 < K; k0 += 64) {
        __syncthreads();
#pragma unroll
        for (int it = 0; it < 4; ++it) {
            int row = it * 32 + ar;
            *(int4*)(&As[row][ac]) = *(const int4*)(A + (long)(m0 + row) * K + k0 + ac);
            *(int4*)(&Bs[row][ac]) = *(const int4*)(Bm + (long)(n0 + row) * K + k0 + ac);
        }
        __syncthreads();
#pragma unroll
        for (int s = 0; s < 2; ++s) {
            bf16x8 af[4], bf[4];
#pragma unroll
            for (int m = 0; m < 4; ++m)
                af[m] = *(const bf16x8*)(&As[wr * 64 + m * 16 + fr][s * 32 + fo]);
#pragma unroll
            for (int n = 0; n < 4; ++n)
                bf[n] = *(const bf16x8*)(&Bs[wc * 64 + n * 16 + fr][s * 32 + fo]);
#pragma unroll
            for (int m = 0; m < 4; ++m)
#pragma unroll
                for (int n = 0; n < 4; ++n)
                    acc[m][n] = __builtin_amdgcn_mfma_f32_16x16x32_bf16(af[m], bf[n], acc[m][n], 0, 0, 0);
        }
    }
    int fq = (lane >> 4) * 4;
#pragma unroll
    for (int m = 0; m < 4; ++m)
#pragma unroll
        for (int n = 0; n < 4; ++n) {
            int row = m0 + wr * 64 + m * 16 + fq;
            int col = n0 + wc * 64 + n * 16 + fr;
#pragma unroll
            for (int r = 0; r < 4; ++r) {
                float v = acc[m][n][r];
                long idx = (long)(row + r) * N + col;
                if (EPI == 0) {
                    outH[idx] = (__bf16)v;
                } else if (EPI == 1) {
                    if (bias) v += bias[col];
                    if (resid) v += resid[idx];
                    outF[idx] = v;
                } else {
                    float b1v = (col < nbias) ? bias[col] : 0.0f;
                    float b2v = (col < nbias) ? bias2[col] : 0.0f;
                    float xv = h1[idx] + b1v;
                    float sw = xv * (1.0f + __expf(-xv));
                    outH[idx] = (__bf16)(sw * (v + b2v));
                }
            }
        }
}

// ---------------- flash attention (causal) ----------------
// grid (T/64, B*H), 256 threads = 4 waves, wave w handles q rows [q0+16w, q0+16w+16)
__global__ __launch_bounds__(256) void k_attn(const __bf16* __restrict__ Q,
                                              const __bf16* __restrict__ Kg,
                                              const __bf16* __restrict__ Vg,
                                              __bf16* __restrict__ O) {
    __shared__ __align__(16) __bf16 Ks[64][72];
    __shared__ __align__(16) __bf16 Vt[64][72];  // Vt[feat][key]
    __shared__ __align__(16) __bf16 Ps[4][16][72];
    int tid = threadIdx.x, lane = tid & 63, w = tid >> 6;
    int q0 = blockIdx.x * 64;
    int bh = blockIdx.y;
    int b = bh >> 4, h = bh & 15;
    const long base = ((long)b * Tv) * Cv + h * HSv;
    int fr = lane & 15, fo = (lane >> 4) * 8, fq = (lane >> 4) * 4;
    int ac = (tid & 7) * 8;
    // Q fragments (A layout): row = fr, k = fo (+32)
    int qrow = q0 + w * 16 + fr;
    bf16x8 qf0 = *(const bf16x8*)(Q + base + (long)qrow * Cv + fo);
    bf16x8 qf1 = *(const bf16x8*)(Q + base + (long)qrow * Cv + 32 + fo);
    f32x4 o[4] = {};
    float mrow[4], lrow[4];
#pragma unroll
    for (int r = 0; r < 4; ++r) { mrow[r] = -INFINITY; lrow[r] = 0.0f; }
    for (int j0 = 0; j0 <= q0; j0 += 64) {
        __syncthreads();
#pragma unroll
        for (int it = 0; it < 2; ++it) {
            int row = it * 32 + (tid >> 3);
            *(int4*)(&Ks[row][ac]) = *(const int4*)(Kg + base + (long)(j0 + row) * Cv + ac);
            int4 vv = *(const int4*)(Vg + base + (long)(j0 + row) * Cv + ac);
            const __bf16* vp = (const __bf16*)&vv;
#pragma unroll
            for (int i = 0; i < 8; ++i) Vt[ac + i][row] = vp[i];
        }
        __syncthreads();
        f32x4 s[4];
#pragma unroll
        for (int kk = 0; kk < 4; ++kk) {
            f32x4 z = {};
            bf16x8 kf0 = *(const bf16x8*)(&Ks[kk * 16 + fr][fo]);
            bf16x8 kf1 = *(const bf16x8*)(&Ks[kk * 16 + fr][32 + fo]);
            z = __builtin_amdgcn_mfma_f32_16x16x32_bf16(qf0, kf0, z, 0, 0, 0);
            z = __builtin_amdgcn_mfma_f32_16x16x32_bf16(qf1, kf1, z, 0, 0, 0);
            s[kk] = z;
        }
        bool diag = (j0 == q0);
#pragma unroll
        for (int r = 0; r < 4; ++r) {
#pragma unroll
            for (int kk = 0; kk < 4; ++kk) {
                float v = s[kk][r] * 0.125f;
                if (diag) {
                    int key = kk * 16 + fr;
                    int qr = w * 16 + fq + r;
                    if (key > qr) v = -INFINITY;
                }
                s[kk][r] = v;
            }
            float mx = fmaxf(fmaxf(s[0][r], s[1][r]), fmaxf(s[2][r], s[3][r]));
#pragma unroll
            for (int msk = 1; msk < 16; msk <<= 1) mx = fmaxf(mx, __shfl_xor(mx, msk));
            float mn = fmaxf(mrow[r], mx);
            float alpha = __expf(mrow[r] - mn);
            mrow[r] = mn;
            float rs = 0.0f;
#pragma unroll
            for (int kk = 0; kk < 4; ++kk) {
                float pv = __expf(s[kk][r] - mn);
                s[kk][r] = pv;
                rs += pv;
            }
#pragma unroll
            for (int msk = 1; msk < 16; msk <<= 1) rs += __shfl_xor(rs, msk);
            lrow[r] = lrow[r] * alpha + rs;
#pragma unroll
            for (int f = 0; f < 4; ++f) o[f][r] *= alpha;
#pragma unroll
            for (int kk = 0; kk < 4; ++kk) Ps[w][fq + r][kk * 16 + fr] = (__bf16)s[kk][r];
        }
        __syncthreads();  // P visible (and uniform across block)
        bf16x8 pa0 = *(const bf16x8*)(&Ps[w][fr][fo]);
        bf16x8 pa1 = *(const bf16x8*)(&Ps[w][fr][32 + fo]);
#pragma unroll
        for (int f = 0; f < 4; ++f) {
            bf16x8 v0 = *(const bf16x8*)(&Vt[f * 16 + fr][fo]);
            bf16x8 v1 = *(const bf16x8*)(&Vt[f * 16 + fr][32 + fo]);
            o[f] = __builtin_amdgcn_mfma_f32_16x16x32_bf16(pa0, v0, o[f], 0, 0, 0);
            o[f] = __builtin_amdgcn_mfma_f32_16x16x32_bf16(pa1, v1, o[f], 0, 0, 0);
        }
    }
#pragma unroll
    for (int f = 0; f < 4; ++f)
#pragma unroll
        for (int r = 0; r < 4; ++r) {
            int row = q0 + w * 16 + fq + r;
            int col = f * 16 + fr;
            O[base + (long)row * Cv + col] = (__bf16)(o[f][r] / lrow[r]);
        }
}

// ---------------- launch ----------------
extern "C" void kernel_launch(void* const* d_in, const int* in_sizes, int n_in,
                              void* d_out, int out_size, void* d_ws, size_t ws_size,
                              hipStream_t stream) {
    const float* x    = (const float*)d_in[0];
    const float* ln1w = (const float*)d_in[1];
    const float* Wq   = (const float*)d_in[2];
    const float* Wk   = (const float*)d_in[3];
    const float* Wv   = (const float*)d_in[4];
    const float* Wo   = (const float*)d_in[5];
    const float* bo   = (const float*)d_in[6];
    const float* w1   = (const float*)d_in[7];
    const float* b1   = (const float*)d_in[8];
    const float* w2   = (const float*)d_in[9];
    const float* b2   = (const float*)d_in[10];
    const float* w3   = (const float*)d_in[11];
    const float* b3   = (const float*)d_in[12];
    const float* ln2w = (const float*)d_in[13];
    const float* cosT = (const float*)d_in[14];
    const float* sinT = (const float*)d_in[15];
    float* out = (float*)d_out;

    char* p = (char*)d_ws;
    auto alloc = [&](size_t bytes) {
        char* r = p;
        p += (bytes + 255) & ~(size_t)255;
        return r;
    };
    float*  x1f = (float*)alloc((size_t)Mv * Cv * 4);   // becomes x2 in-place
    float*  x3f = (float*)alloc((size_t)Mv * Cv * 4);
    __bf16* x1h = (__bf16*)alloc((size_t)Mv * Cv * 2);
    __bf16* x3h = (__bf16*)alloc((size_t)Mv * Cv * 2);
    __bf16* qh  = (__bf16*)alloc((size_t)Mv * Cv * 2);
    __bf16* kh  = (__bf16*)alloc((size_t)Mv * Cv * 2);
    __bf16* vh  = (__bf16*)alloc((size_t)Mv * Cv * 2);
    __bf16* ah  = (__bf16*)alloc((size_t)Mv * Cv * 2);
    float*  h1f = (float*)alloc((size_t)Mv * HIDP * 4);
    __bf16* hh  = (__bf16*)alloc((size_t)Mv * HIDP * 2);
    __bf16* wqh = (__bf16*)alloc((size_t)Cv * Cv * 2);
    __bf16* wkh = (__bf16*)alloc((size_t)Cv * Cv * 2);
    __bf16* wvh = (__bf16*)alloc((size_t)Cv * Cv * 2);
    __bf16* woh = (__bf16*)alloc((size_t)Cv * Cv * 2);
    __bf16* w1h = (__bf16*)alloc((size_t)HIDP * Cv * 2);
    __bf16* w2h = (__bf16*)alloc((size_t)HIDP * Cv * 2);
    __bf16* w3h = (__bf16*)alloc((size_t)Cv * HIDP * 2);

    const long nCC = (long)Cv * Cv;
    k_cast<<<1024, 256, 0, stream>>>(Wq, wqh, nCC, nCC);
    k_cast<<<1024, 256, 0, stream>>>(Wk, wkh, nCC, nCC);
    k_cast<<<1024, 256, 0, stream>>>(Wv, wvh, nCC, nCC);
    k_cast<<<1024, 256, 0, stream>>>(Wo, woh, nCC, nCC);
    k_cast<<<1024, 256, 0, stream>>>(w1, w1h, (long)HIDv * Cv, (long)HIDP * Cv);
    k_cast<<<1024, 256, 0, stream>>>(w2, w2h, (long)HIDv * Cv, (long)HIDP * Cv);
    k_cast_padcols<<<1024, 256, 0, stream>>>(w3, w3h, Cv, HIDv, HIDP);

    k_rmsnorm<<<Mv, 256, 0, stream>>>(x, ln1w, x1f, x1h);

    dim3 g1(Cv / 128, Mv / 128);
    k_gemm<0><<<g1, 256, 0, stream>>>(x1h, wqh, Mv, Cv, Cv, nullptr, qh, nullptr, 0, nullptr, nullptr, nullptr);
    k_gemm<0><<<g1, 256, 0, stream>>>(x1h, wkh, Mv, Cv, Cv, nullptr, kh, nullptr, 0, nullptr, nullptr, nullptr);
    k_gemm<0><<<g1, 256, 0, stream>>>(x1h, wvh, Mv, Cv, Cv, nullptr, vh, nullptr, 0, nullptr, nullptr, nullptr);

    k_rope<<<(Mv * 512 + 255) / 256, 256, 0, stream>>>(qh, kh, cosT, sinT);

    k_attn<<<dim3(Tv / 64, Bv * Hv), 256, 0, stream>>>(qh, kh, vh, ah);

    // x2 = x1 + attn @ Wo^T + bo   (writes back into x1f; per-thread read-then-write, safe)
    k_gemm<1><<<g1, 256, 0, stream>>>(ah, woh, Mv, Cv, Cv, x1f, nullptr, bo, Cv, x1f, nullptr, nullptr);

    k_rmsnorm<<<Mv, 256, 0, stream>>>(x1f, ln2w, x3f, x3h);

    dim3 g2(HIDP / 128, Mv / 128);
    // h1 = x3 @ w1^T (f32, no bias yet)
    k_gemm<1><<<g2, 256, 0, stream>>>(x3h, w1h, Mv, HIDP, Cv, h1f, nullptr, nullptr, 0, nullptr, nullptr, nullptr);
    // h = swish_bug(h1 + b1) * (x3 @ w2^T + b2)  -> bf16
    k_gemm<3><<<g2, 256, 0, stream>>>(x3h, w2h, Mv, HIDP, Cv, nullptr, hh, b1, HIDv, nullptr, h1f, b2);
    // out = x3 + h @ w3^T + b3   (f32)
    k_gemm<1><<<g1, 256, 0, stream>>>(hh, w3h, Mv, Cv, HIDP, out, nullptr, b3, Cv, x3f, nullptr, nullptr);
}

// Round 2
// 452.526 us; speedup vs baseline: 1.1873x; 1.1873x over previous
//
#include <hip/hip_runtime.h>
#include <hip/hip_bf16.h>

#define Bv 2
#define Tv 2048
#define Cv 1024
#define Hv 16
#define HSv 64
#define HIDv 2730
#define HIDP 2816
#define Mv 4096

using bf16x8 = __attribute__((ext_vector_type(8))) __bf16;
using f32x4  = __attribute__((ext_vector_type(4))) float;

// global -> LDS direct copy, 16B per lane. LDS side must be linear in lane order.
__device__ __forceinline__ void gload_lds16(const void* g, void* l) {
    auto gp = (const __attribute__((address_space(1))) unsigned int*)(unsigned long long)(uintptr_t)g;
    auto lp = (__attribute__((address_space(3))) unsigned int*)(unsigned int)(uintptr_t)l;
    __builtin_amdgcn_global_load_lds(gp, lp, 16, 0, 0);
}

// ---------------- cast / pad kernels ----------------
__global__ void k_cast(const float* __restrict__ src, __bf16* __restrict__ dst,
                       long n_src, long n_total) {
    long i = (long)blockIdx.x * blockDim.x + threadIdx.x;
    long stride = (long)gridDim.x * blockDim.x;
    for (; i < n_total; i += stride)
        dst[i] = (i < n_src) ? (__bf16)src[i] : (__bf16)0.0f;
}

__global__ void k_cast_padcols(const float* __restrict__ src, __bf16* __restrict__ dst,
                               int rows, int sc, int dc) {
    long total = (long)rows * dc;
    long i = (long)blockIdx.x * blockDim.x + threadIdx.x;
    long stride = (long)gridDim.x * blockDim.x;
    for (; i < total; i += stride) {
        int r = (int)(i / dc), c = (int)(i % dc);
        dst[i] = (c < sc) ? (__bf16)src[(long)r * sc + c] : (__bf16)0.0f;
    }
}

// ---------------- rmsnorm ----------------
__global__ __launch_bounds__(256) void k_rmsnorm(const float* __restrict__ x,
                                                 const float* __restrict__ w,
                                                 float* __restrict__ yf,
                                                 __bf16* __restrict__ yh) {
    int row = blockIdx.x;
    const float4* xr = (const float4*)(x + (size_t)row * Cv);
    float4 a = xr[threadIdx.x];
    float ss = a.x * a.x + a.y * a.y + a.z * a.z + a.w * a.w;
#pragma unroll
    for (int m = 1; m < 64; m <<= 1) ss += __shfl_xor(ss, m);
    __shared__ float red[4];
    if ((threadIdx.x & 63) == 0) red[threadIdx.x >> 6] = ss;
    __syncthreads();
    float tot = red[0] + red[1] + red[2] + red[3];
    float sc = rsqrtf(tot * (1.0f / Cv) + 1e-6f);
    float4 wv = ((const float4*)w)[threadIdx.x];
    float4 o;
    o.x = a.x * sc * wv.x; o.y = a.y * sc * wv.y;
    o.z = a.z * sc * wv.z; o.w = a.w * sc * wv.w;
    ((float4*)(yf + (size_t)row * Cv))[threadIdx.x] = o;
    __bf16* yp = yh + (size_t)row * Cv + threadIdx.x * 4;
    yp[0] = (__bf16)o.x; yp[1] = (__bf16)o.y; yp[2] = (__bf16)o.z; yp[3] = (__bf16)o.w;
}

// ---------------- RoPE: Q in place; K -> KR[bh][t][64] pre-swizzled ----------------
__global__ void k_rope(__bf16* __restrict__ Q, const __bf16* __restrict__ Kin,
                       __bf16* __restrict__ KR,
                       const float* __restrict__ cosT, const float* __restrict__ sinT) {
    long total = (long)Mv * 512;
    long i = (long)blockIdx.x * blockDim.x + threadIdx.x;
    if (i >= total) return;
    int row = (int)(i >> 9);
    int p = (int)(i & 511);
    int h = p >> 5, ii = p & 31;
    int t = row & (Tv - 1), b = row >> 11;
    float c = cosT[t * 32 + ii], s = sinT[t * 32 + ii];
    long idx = (long)row * Cv + h * 64 + 2 * ii;
    float x0 = (float)Q[idx], x1 = (float)Q[idx + 1];
    Q[idx]     = (__bf16)(x0 * c - x1 * s);
    Q[idx + 1] = (__bf16)(x0 * s + x1 * c);
    float y0 = (float)Kin[idx], y1 = (float)Kin[idx + 1];
    __bf16 k0 = (__bf16)(y0 * c - y1 * s);
    __bf16 k1 = (__bf16)(y0 * s + y1 * c);
    int bh = b * 16 + h;
    int colb = (4 * ii) ^ ((t & 7) << 4);   // swizzled byte col within 128B row
    __bf16 pk[2] = {k0, k1};
    *(unsigned int*)((char*)(KR + ((long)bh * Tv + t) * 64) + colb) = *(unsigned int*)pk;
}

// ---------------- V transpose: VT[bh][f][t], pre-swizzled per 64-key tile ----------------
__global__ __launch_bounds__(256) void k_vtrans(const __bf16* __restrict__ V,
                                                __bf16* __restrict__ VT) {
    __shared__ __bf16 Ts[64][72];
    int t0 = blockIdx.x * 64;
    int bh = blockIdx.y, b = bh >> 4, h = bh & 15;
    const long base = ((long)b * Tv) * Cv + h * 64;
    int tid = threadIdx.x;
    int rr = tid >> 3, cc = (tid & 7) * 8;
#pragma unroll
    for (int it = 0; it < 2; ++it) {
        int row = it * 32 + rr;
        *(int4*)&Ts[row][cc] = *(const int4*)(V + base + (long)(t0 + row) * Cv + cc);
    }
    __syncthreads();
#pragma unroll
    for (int it = 0; it < 2; ++it) {
        int f = it * 32 + rr;
        int tcol = cc ^ ((f & 7) << 3);   // logical t-offset stored at physical cc
        __bf16 tmp[8];
#pragma unroll
        for (int j = 0; j < 8; ++j) tmp[j] = Ts[tcol + j][f];
        *(int4*)(VT + ((long)bh * 64 + f) * Tv + t0 + cc) = *(int4*)tmp;
    }
}

// ---------------- GEMM: C[M,N] = A[M,K] @ B[N,K]^T, m97 structure ----------------
// EPI 1: outF = acc (+bias[col]) (+resid[idx])
// EPI 3: outH = swish_bug(h1[idx]+b1[col]) * (acc + b2[col])
// EPI 4: route cols to qOut/kOut/vOut (bf16, each [M][1024])
template <int BM, int EPI>
__global__ __launch_bounds__(256) void k_gemm(
    const __bf16* __restrict__ A, const __bf16* __restrict__ Bm,
    int M, int N, int K,
    float* __restrict__ outF, __bf16* __restrict__ outH,
    const float* __restrict__ bias, int nbias,
    const float* __restrict__ resid,
    const float* __restrict__ h1, const float* __restrict__ bias2,
    __bf16* __restrict__ qOut, __bf16* __restrict__ kOut, __bf16* __restrict__ vOut) {
    constexpr int NN = (BM == 128) ? 4 : 2;
    __shared__ __align__(16) __bf16 As[BM][64];
    __shared__ __align__(16) __bf16 Bs[128][64];
    int tid = threadIdx.x, lane = tid & 63, wave = tid >> 6;
    int m0 = blockIdx.y * BM, n0 = blockIdx.x * 128;
    int wro = (BM == 128) ? (wave >> 1) * 64 : 0;
    int wco = (BM == 128) ? (wave & 1) * 64 : wave * 32;
    int fr = lane & 15, fo = (lane >> 4) * 8;
    int lr = lane >> 3, lc = (lane & 7) * 8;
    f32x4 acc[4][NN] = {};
    for (int k0 = 0; k0 < K; k0 += 64) {
        __syncthreads();
        int arow0 = wave * (BM / 4);
#pragma unroll
        for (int i = 0; i < BM / 32; ++i) {
            int r = arow0 + i * 8 + lr;
            gload_lds16(A + (long)(m0 + r) * K + k0 + lc, &As[r][lc]);
        }
        int brow0 = wave * 32;
#pragma unroll
        for (int i = 0; i < 4; ++i) {
            int r = brow0 + i * 8 + lr;
            gload_lds16(Bm + (long)(n0 + r) * K + k0 + lc, &Bs[r][lc]);
        }
        __syncthreads();
#pragma unroll
        for (int s = 0; s < 2; ++s) {
            bf16x8 af[4], bf[NN];
#pragma unroll
            for (int m = 0; m < 4; ++m)
                af[m] = *(const bf16x8*)(&As[wro + m * 16 + fr][s * 32 + fo]);
#pragma unroll
            for (int n = 0; n < NN; ++n)
                bf[n] = *(const bf16x8*)(&Bs[wco + n * 16 + fr][s * 32 + fo]);
#pragma unroll
            for (int m = 0; m < 4; ++m)
#pragma unroll
                for (int n = 0; n < NN; ++n)
                    acc[m][n] = __builtin_amdgcn_mfma_f32_16x16x32_bf16(af[m], bf[n], acc[m][n], 0, 0, 0);
        }
    }
    int fq = (lane >> 4) * 4;
#pragma unroll
    for (int m = 0; m < 4; ++m)
#pragma unroll
        for (int n = 0; n < NN; ++n) {
            int row = m0 + wro + m * 16 + fq;
            int col = n0 + wco + n * 16 + fr;
#pragma unroll
            for (int r = 0; r < 4; ++r) {
                float v = acc[m][n][r];
                long idx = (long)(row + r) * N + col;
                if (EPI == 1) {
                    if (bias) v += bias[col];
                    if (resid) v += resid[idx];
                    outF[idx] = v;
                } else if (EPI == 3) {
                    float b1v = (col < nbias) ? bias[col] : 0.0f;
                    float b2v = (col < nbias) ? bias2[col] : 0.0f;
                    float xv = h1[idx] + b1v;
                    float sw = xv * (1.0f + __expf(-xv));
                    outH[idx] = (__bf16)(sw * (v + b2v));
                } else {  // EPI 4
                    int part = col >> 10, c = col & 1023;
                    __bf16* dst = (part == 0) ? qOut : (part == 1) ? kOut : vOut;
                    dst[(long)(row + r) * 1024 + c] = (__bf16)v;
                }
            }
        }
}

// ---------------- flash attention (causal), swizzled LDS via pre-swizzled global ----------------
__global__ __launch_bounds__(256) void k_attn(const __bf16* __restrict__ Q,
                                              const __bf16* __restrict__ KR,
                                              const __bf16* __restrict__ VT,
                                              __bf16* __restrict__ O) {
    __shared__ __align__(16) __bf16 Ks[64][64];
    __shared__ __align__(16) __bf16 Vs[64][64];
    __shared__ __align__(16) __bf16 Ps[4][16][64];
    int tid = threadIdx.x, lane = tid & 63, w = tid >> 6;
    int bh = blockIdx.x >> 5;
    int qt = 31 - (blockIdx.x & 31);          // longest blocks dispatch first
    int q0 = qt * 64;
    int b = bh >> 4, h = bh & 15;
    const long qbase = ((long)b * Tv) * Cv + h * HSv;
    const long kbase = (long)bh * Tv * 64;
    const long vbase = (long)bh * 64 * Tv;
    int fr = lane & 15, fog = lane >> 4;
    int fo = fog * 8, fq = fog * 4;
    int lr = lane >> 3, lc8 = (lane & 7) * 8;
    int qrow = q0 + w * 16 + fr;
    bf16x8 qf0 = *(const bf16x8*)(Q + qbase + (long)qrow * Cv + fo);
    bf16x8 qf1 = *(const bf16x8*)(Q + qbase + (long)qrow * Cv + 32 + fo);
    f32x4 o[4] = {};
    float mrow[4], lrow[4];
#pragma unroll
    for (int r = 0; r < 4; ++r) { mrow[r] = -INFINITY; lrow[r] = 0.0f; }
    for (int j0 = 0; j0 <= q0; j0 += 64) {
        __syncthreads();                       // prior-iter LDS reads done
#pragma unroll
        for (int i = 0; i < 2; ++i) {
            int rk = w * 16 + i * 8 + lr;
            gload_lds16(KR + kbase + (long)(j0 + rk) * 64 + lc8, &Ks[rk][lc8]);
            gload_lds16(VT + vbase + (long)rk * Tv + j0 + lc8, &Vs[rk][lc8]);
        }
        __syncthreads();                       // staged (vmcnt drained by barrier)
        f32x4 s4[4];
#pragma unroll
        for (int kk = 0; kk < 4; ++kk) {
            int key = kk * 16 + fr;
            const char* krow = (const char*)&Ks[key][0];
            bf16x8 kf0 = *(const bf16x8*)(krow + ((fo * 2) ^ ((key & 7) << 4)));
            bf16x8 kf1 = *(const bf16x8*)(krow + ((64 + fo * 2) ^ ((key & 7) << 4)));
            f32x4 z = {};
            z = __builtin_amdgcn_mfma_f32_16x16x32_bf16(qf0, kf0, z, 0, 0, 0);
            z = __builtin_amdgcn_mfma_f32_16x16x32_bf16(qf1, kf1, z, 0, 0, 0);
            s4[kk] = z;
        }
        bool diag = (j0 == q0);
#pragma unroll
        for (int r = 0; r < 4; ++r) {
#pragma unroll
            for (int kk = 0; kk < 4; ++kk) {
                float v = s4[kk][r] * 0.125f;
                if (diag) {
                    int key = kk * 16 + fr;
                    int qr = w * 16 + fq + r;
                    if (key > qr) v = -INFINITY;
                }
                s4[kk][r] = v;
            }
            float mx = fmaxf(fmaxf(s4[0][r], s4[1][r]), fmaxf(s4[2][r], s4[3][r]));
#pragma unroll
            for (int msk = 1; msk < 16; msk <<= 1) mx = fmaxf(mx, __shfl_xor(mx, msk));
            float mn = fmaxf(mrow[r], mx);
            float alpha = __expf(mrow[r] - mn);
            mrow[r] = mn;
            float rs = 0.0f;
#pragma unroll
            for (int kk = 0; kk < 4; ++kk) {
                float pv = __expf(s4[kk][r] - mn);
                s4[kk][r] = pv;
                rs += pv;
            }
#pragma unroll
            for (int msk = 1; msk < 16; msk <<= 1) rs += __shfl_xor(rs, msk);
            lrow[r] = lrow[r] * alpha + rs;
#pragma unroll
            for (int f = 0; f < 4; ++f) o[f][r] *= alpha;
            char* prow = (char*)&Ps[w][fq + r][0];
#pragma unroll
            for (int kk = 0; kk < 4; ++kk) {
                int colb = ((kk * 16 + fr) * 2) ^ (((fq + r) & 7) << 4);
                *(__bf16*)(prow + colb) = (__bf16)s4[kk][r];
            }
        }
        // PV (per-wave P tile; intra-wave LDS dependency, no barrier needed)
        const char* prd = (const char*)&Ps[w][fr][0];
        bf16x8 pa0 = *(const bf16x8*)(prd + ((fo * 2) ^ ((fr & 7) << 4)));
        bf16x8 pa1 = *(const bf16x8*)(prd + ((64 + fo * 2) ^ ((fr & 7) << 4)));
#pragma unroll
        for (int f = 0; f < 4; ++f) {
            int vrow = f * 16 + fr;
            const char* vrd = (const char*)&Vs[vrow][0];
            bf16x8 v0 = *(const bf16x8*)(vrd + ((fo * 2) ^ ((vrow & 7) << 4)));
            bf16x8 v1 = *(const bf16x8*)(vrd + ((64 + fo * 2) ^ ((vrow & 7) << 4)));
            o[f] = __builtin_amdgcn_mfma_f32_16x16x32_bf16(pa0, v0, o[f], 0, 0, 0);
            o[f] = __builtin_amdgcn_mfma_f32_16x16x32_bf16(pa1, v1, o[f], 0, 0, 0);
        }
    }
#pragma unroll
    for (int f = 0; f < 4; ++f)
#pragma unroll
        for (int r = 0; r < 4; ++r) {
            int row = q0 + w * 16 + fq + r;
            int col = f * 16 + fr;
            O[qbase + (long)row * Cv + col] = (__bf16)(o[f][r] / lrow[r]);
        }
}

// ---------------- launch ----------------
extern "C" void kernel_launch(void* const* d_in, const int* in_sizes, int n_in,
                              void* d_out, int out_size, void* d_ws, size_t ws_size,
                              hipStream_t stream) {
    const float* x    = (const float*)d_in[0];
    const float* ln1w = (const float*)d_in[1];
    const float* Wq   = (const float*)d_in[2];
    const float* Wk   = (const float*)d_in[3];
    const float* Wv   = (const float*)d_in[4];
    const float* Wo   = (const float*)d_in[5];
    const float* bo   = (const float*)d_in[6];
    const float* w1   = (const float*)d_in[7];
    const float* b1   = (const float*)d_in[8];
    const float* w2   = (const float*)d_in[9];
    const float* b2   = (const float*)d_in[10];
    const float* w3   = (const float*)d_in[11];
    const float* b3   = (const float*)d_in[12];
    const float* ln2w = (const float*)d_in[13];
    const float* cosT = (const float*)d_in[14];
    const float* sinT = (const float*)d_in[15];
    float* out = (float*)d_out;

    char* p = (char*)d_ws;
    auto alloc = [&](size_t bytes) {
        char* r = p;
        p += (bytes + 255) & ~(size_t)255;
        return r;
    };
    // region reused by h1f (x1f..ah = 48MB, h1f needs 46.1MB)
    char* big = p;
    float*  x1f = (float*)alloc((size_t)Mv * Cv * 4);
    __bf16* qh  = (__bf16*)alloc((size_t)Mv * Cv * 2);
    __bf16* kh  = (__bf16*)alloc((size_t)Mv * Cv * 2);
    __bf16* vh  = (__bf16*)alloc((size_t)Mv * Cv * 2);
    __bf16* ah  = (__bf16*)alloc((size_t)Mv * Cv * 2);
    float*  h1f = (float*)big;                            // alias (live only in FFN phase)
    float*  x3f = (float*)alloc((size_t)Mv * Cv * 4);
    __bf16* x1h = (__bf16*)alloc((size_t)Mv * Cv * 2);
    __bf16* VT  = (__bf16*)x1h;                           // alias (x1h dead after QKV GEMM)
    __bf16* x3h = (__bf16*)alloc((size_t)Mv * Cv * 2);
    __bf16* KR  = (__bf16*)alloc((size_t)Mv * 64 * 2);    // [bh][T][64]
    __bf16* hh  = (__bf16*)alloc((size_t)Mv * HIDP * 2);
    __bf16* wqkvh = (__bf16*)alloc((size_t)3072 * Cv * 2);
    __bf16* woh = (__bf16*)alloc((size_t)Cv * Cv * 2);
    __bf16* w1h = (__bf16*)alloc((size_t)HIDP * Cv * 2);
    __bf16* w2h = (__bf16*)alloc((size_t)HIDP * Cv * 2);
    __bf16* w3h = (__bf16*)alloc((size_t)Cv * HIDP * 2);

    const long nCC = (long)Cv * Cv;
    k_cast<<<1024, 256, 0, stream>>>(Wq, wqkvh, nCC, nCC);
    k_cast<<<1024, 256, 0, stream>>>(Wk, wqkvh + nCC, nCC, nCC);
    k_cast<<<1024, 256, 0, stream>>>(Wv, wqkvh + 2 * nCC, nCC, nCC);
    k_cast<<<1024, 256, 0, stream>>>(Wo, woh, nCC, nCC);
    k_cast<<<1024, 256, 0, stream>>>(w1, w1h, (long)HIDv * Cv, (long)HIDP * Cv);
    k_cast<<<1024, 256, 0, stream>>>(w2, w2h, (long)HIDv * Cv, (long)HIDP * Cv);
    k_cast_padcols<<<1024, 256, 0, stream>>>(w3, w3h, Cv, HIDv, HIDP);

    k_rmsnorm<<<Mv, 256, 0, stream>>>(x, ln1w, x1f, x1h);

    // fused QKV GEMM: N = 3072
    k_gemm<128, 4><<<dim3(24, 32), 256, 0, stream>>>(x1h, wqkvh, Mv, 3072, Cv,
        nullptr, nullptr, nullptr, 0, nullptr, nullptr, nullptr, qh, kh, vh);

    k_rope<<<(Mv * 512 + 255) / 256, 256, 0, stream>>>(qh, kh, KR, cosT, sinT);
    k_vtrans<<<dim3(Tv / 64, Bv * Hv), 256, 0, stream>>>(vh, VT);

    k_attn<<<1024, 256, 0, stream>>>(qh, KR, VT, ah);

    // x2 = x1 + attn @ Wo^T + bo  (into x1f)
    k_gemm<64, 1><<<dim3(8, 64), 256, 0, stream>>>(ah, woh, Mv, Cv, Cv,
        x1f, nullptr, bo, Cv, x1f, nullptr, nullptr, nullptr, nullptr, nullptr);

    k_rmsnorm<<<Mv, 256, 0, stream>>>(x1f, ln2w, x3f, x3h);

    // h1 = x3 @ w1^T (f32)
    k_gemm<128, 1><<<dim3(HIDP / 128, 32), 256, 0, stream>>>(x3h, w1h, Mv, HIDP, Cv,
        h1f, nullptr, nullptr, 0, nullptr, nullptr, nullptr, nullptr, nullptr, nullptr);
    // h = swish_bug(h1+b1) * (x3 @ w2^T + b2)
    k_gemm<128, 3><<<dim3(HIDP / 128, 32), 256, 0, stream>>>(x3h, w2h, Mv, HIDP, Cv,
        nullptr, hh, b1, HIDv, nullptr, h1f, b2, nullptr, nullptr, nullptr);
    // out = x3 + h @ w3^T + b3
    k_gemm<64, 1><<<dim3(8, 64), 256, 0, stream>>>(hh, w3h, Mv, Cv, HIDP,
        out, nullptr, b3, Cv, x3f, nullptr, nullptr, nullptr, nullptr, nullptr);
}

// Round 3
// 377.780 us; speedup vs baseline: 1.4222x; 1.1979x over previous
//
#include <hip/hip_runtime.h>
#include <hip/hip_bf16.h>

#define Bv 2
#define Tv 2048
#define Cv 1024
#define Hv 16
#define HSv 64
#define HIDv 2730
#define HIDP 2816
#define Mv 4096

using bf16x8 = __attribute__((ext_vector_type(8))) __bf16;
using f32x4  = __attribute__((ext_vector_type(4))) float;

__device__ __forceinline__ void gload_lds16(const void* g, void* l) {
    auto gp = (const __attribute__((address_space(1))) unsigned int*)(unsigned long long)(uintptr_t)g;
    auto lp = (__attribute__((address_space(3))) unsigned int*)(unsigned int)(uintptr_t)l;
    __builtin_amdgcn_global_load_lds(gp, lp, 16, 0, 0);
}

// ---------------- fused weight cast ----------------
struct CastSeg { const float* s; __bf16* d; long nsrc; long ntot; int sc; int dc; };
struct CastArgs { CastSeg seg[7]; };

__global__ __launch_bounds__(256) void k_castall(CastArgs a) {
    long gid = (long)blockIdx.x * 256 + threadIdx.x;
    long gstr = (long)gridDim.x * 256;
#pragma unroll 1
    for (int g = 0; g < 7; ++g) {
        CastSeg sg = a.seg[g];
        if (sg.sc == 0) {
            long n4 = sg.ntot >> 2;
            for (long i = gid; i < n4; i += gstr) {
                long base = i * 4;
                float4 v = {0.f, 0.f, 0.f, 0.f};
                if (base < sg.nsrc) v = *(const float4*)(sg.s + base);
                __bf16 o[4] = {(__bf16)v.x, (__bf16)v.y, (__bf16)v.z, (__bf16)v.w};
                *(unsigned long long*)(sg.d + base) = *(unsigned long long*)o;
            }
        } else {
            for (long i = gid; i < sg.ntot; i += gstr) {
                int r = (int)(i / sg.dc), c = (int)(i % sg.dc);
                sg.d[i] = (c < sg.sc) ? (__bf16)sg.s[(long)r * sg.sc + c] : (__bf16)0.0f;
            }
        }
    }
}

// ---------------- rmsnorm ----------------
__global__ __launch_bounds__(256) void k_rmsnorm(const float* __restrict__ x,
                                                 const float* __restrict__ w,
                                                 float* __restrict__ yf,
                                                 __bf16* __restrict__ yh) {
    int row = blockIdx.x;
    const float4* xr = (const float4*)(x + (size_t)row * Cv);
    float4 a = xr[threadIdx.x];
    float ss = a.x * a.x + a.y * a.y + a.z * a.z + a.w * a.w;
#pragma unroll
    for (int m = 1; m < 64; m <<= 1) ss += __shfl_xor(ss, m);
    __shared__ float red[4];
    if ((threadIdx.x & 63) == 0) red[threadIdx.x >> 6] = ss;
    __syncthreads();
    float tot = red[0] + red[1] + red[2] + red[3];
    float sc = rsqrtf(tot * (1.0f / Cv) + 1e-6f);
    float4 wv = ((const float4*)w)[threadIdx.x];
    float4 o;
    o.x = a.x * sc * wv.x; o.y = a.y * sc * wv.y;
    o.z = a.z * sc * wv.z; o.w = a.w * sc * wv.w;
    ((float4*)(yf + (size_t)row * Cv))[threadIdx.x] = o;
    __bf16* yp = yh + (size_t)row * Cv + threadIdx.x * 4;
    yp[0] = (__bf16)o.x; yp[1] = (__bf16)o.y; yp[2] = (__bf16)o.z; yp[3] = (__bf16)o.w;
}

// ---------------- RoPE: Q in place; K -> KR[bh][t][64] pre-swizzled ----------------
__global__ void k_rope(__bf16* __restrict__ Q, const __bf16* __restrict__ Kin,
                       __bf16* __restrict__ KR,
                       const float* __restrict__ cosT, const float* __restrict__ sinT) {
    long total = (long)Mv * 512;
    long i = (long)blockIdx.x * blockDim.x + threadIdx.x;
    if (i >= total) return;
    int row = (int)(i >> 9);
    int p = (int)(i & 511);
    int h = p >> 5, ii = p & 31;
    int t = row & (Tv - 1), b = row >> 11;
    float c = cosT[t * 32 + ii], s = sinT[t * 32 + ii];
    long idx = (long)row * Cv + h * 64 + 2 * ii;
    float x0 = (float)Q[idx], x1 = (float)Q[idx + 1];
    Q[idx]     = (__bf16)(x0 * c - x1 * s);
    Q[idx + 1] = (__bf16)(x0 * s + x1 * c);
    float y0 = (float)Kin[idx], y1 = (float)Kin[idx + 1];
    __bf16 k0 = (__bf16)(y0 * c - y1 * s);
    __bf16 k1 = (__bf16)(y0 * s + y1 * c);
    int bh = b * 16 + h;
    int colb = (4 * ii) ^ ((t & 7) << 4);
    __bf16 pk[2] = {k0, k1};
    *(unsigned int*)((char*)(KR + ((long)bh * Tv + t) * 64) + colb) = *(unsigned int*)pk;
}

// ---------------- V transpose: VT[bh][f][t], pre-swizzled per 64-key tile ----------------
__global__ __launch_bounds__(256) void k_vtrans(const __bf16* __restrict__ V,
                                                __bf16* __restrict__ VT) {
    __shared__ __bf16 Ts[64][72];
    int t0 = blockIdx.x * 64;
    int bh = blockIdx.y, b = bh >> 4, h = bh & 15;
    const long base = ((long)b * Tv) * Cv + h * 64;
    int tid = threadIdx.x;
    int rr = tid >> 3, cc = (tid & 7) * 8;
#pragma unroll
    for (int it = 0; it < 2; ++it) {
        int row = it * 32 + rr;
        *(int4*)&Ts[row][cc] = *(const int4*)(V + base + (long)(t0 + row) * Cv + cc);
    }
    __syncthreads();
#pragma unroll
    for (int it = 0; it < 2; ++it) {
        int f = it * 32 + rr;
        int tcol = cc ^ ((f & 7) << 3);
        __bf16 tmp[8];
#pragma unroll
        for (int j = 0; j < 8; ++j) tmp[j] = Ts[tcol + j][f];
        *(int4*)(VT + ((long)bh * 64 + f) * Tv + t0 + cc) = *(int4*)tmp;
    }
}

// ---------------- GEMM: C[M,N] = A[M,K] @ B[N,K]^T, m97 structure ----------------
// EPI 1: outF = acc (+bias[col]) (+resid[idx])
// EPI 4: route cols to qOut/kOut/vOut (bf16, each [M][1024])
template <int BM, int EPI>
__global__ __launch_bounds__(256) void k_gemm(
    const __bf16* __restrict__ A, const __bf16* __restrict__ Bm,
    int M, int N, int K,
    float* __restrict__ outF,
    const float* __restrict__ bias,
    const float* __restrict__ resid,
    __bf16* __restrict__ qOut, __bf16* __restrict__ kOut, __bf16* __restrict__ vOut) {
    constexpr int NN = (BM == 128) ? 4 : 2;
    __shared__ __align__(16) __bf16 As[BM][64];
    __shared__ __align__(16) __bf16 Bs[128][64];
    int tid = threadIdx.x, lane = tid & 63, wave = tid >> 6;
    int m0 = blockIdx.y * BM, n0 = blockIdx.x * 128;
    int wro = (BM == 128) ? (wave >> 1) * 64 : 0;
    int wco = (BM == 128) ? (wave & 1) * 64 : wave * 32;
    int fr = lane & 15, fo = (lane >> 4) * 8;
    int lr = lane >> 3, lc = (lane & 7) * 8;
    f32x4 acc[4][NN] = {};
    for (int k0 = 0; k0 < K; k0 += 64) {
        __syncthreads();
        int arow0 = wave * (BM / 4);
#pragma unroll
        for (int i = 0; i < BM / 32; ++i) {
            int r = arow0 + i * 8 + lr;
            gload_lds16(A + (long)(m0 + r) * K + k0 + lc, &As[r][lc]);
        }
        int brow0 = wave * 32;
#pragma unroll
        for (int i = 0; i < 4; ++i) {
            int r = brow0 + i * 8 + lr;
            gload_lds16(Bm + (long)(n0 + r) * K + k0 + lc, &Bs[r][lc]);
        }
        __syncthreads();
#pragma unroll
        for (int s = 0; s < 2; ++s) {
            bf16x8 af[4], bf[NN];
#pragma unroll
            for (int m = 0; m < 4; ++m)
                af[m] = *(const bf16x8*)(&As[wro + m * 16 + fr][s * 32 + fo]);
#pragma unroll
            for (int n = 0; n < NN; ++n)
                bf[n] = *(const bf16x8*)(&Bs[wco + n * 16 + fr][s * 32 + fo]);
#pragma unroll
            for (int m = 0; m < 4; ++m)
#pragma unroll
                for (int n = 0; n < NN; ++n)
                    acc[m][n] = __builtin_amdgcn_mfma_f32_16x16x32_bf16(af[m], bf[n], acc[m][n], 0, 0, 0);
        }
    }
    int fq = (lane >> 4) * 4;
#pragma unroll
    for (int m = 0; m < 4; ++m)
#pragma unroll
        for (int n = 0; n < NN; ++n) {
            int row = m0 + wro + m * 16 + fq;
            int col = n0 + wco + n * 16 + fr;
#pragma unroll
            for (int r = 0; r < 4; ++r) {
                float v = acc[m][n][r];
                long idx = (long)(row + r) * N + col;
                if (EPI == 1) {
                    if (bias) v += bias[col];
                    if (resid) v += resid[idx];
                    outF[idx] = v;
                } else {
                    int part = col >> 10, c = col & 1023;
                    __bf16* dst = (part == 0) ? qOut : (part == 1) ? kOut : vOut;
                    dst[(long)(row + r) * 1024 + c] = (__bf16)v;
                }
            }
        }
}

// ---------------- fused FFN1+FFN2: h = swish_bug(x3@w1^T + b1) * (x3@w2^T + b2) ----------------
__global__ __launch_bounds__(256) void k_ffn(const __bf16* __restrict__ A,
                                             const __bf16* __restrict__ B1,
                                             const __bf16* __restrict__ B2,
                                             const float* __restrict__ b1,
                                             const float* __restrict__ b2,
                                             __bf16* __restrict__ outH) {
    __shared__ __align__(16) __bf16 As[128][64];
    __shared__ __align__(16) __bf16 B1s[64][64];
    __shared__ __align__(16) __bf16 B2s[64][64];
    int tid = threadIdx.x, lane = tid & 63, wave = tid >> 6;
    int m0 = blockIdx.y * 128, n0 = blockIdx.x * 64;
    int fr = lane & 15, fo = (lane >> 4) * 8;
    int lr = lane >> 3, lc = (lane & 7) * 8;
    f32x4 acc1[2][4] = {}, acc2[2][4] = {};
    for (int k0 = 0; k0 < Cv; k0 += 64) {
        __syncthreads();
#pragma unroll
        for (int i = 0; i < 4; ++i) {
            int r = wave * 32 + i * 8 + lr;
            gload_lds16(A + (long)(m0 + r) * Cv + k0 + lc, &As[r][lc]);
        }
#pragma unroll
        for (int i = 0; i < 2; ++i) {
            int r = wave * 16 + i * 8 + lr;
            gload_lds16(B1 + (long)(n0 + r) * Cv + k0 + lc, &B1s[r][lc]);
            gload_lds16(B2 + (long)(n0 + r) * Cv + k0 + lc, &B2s[r][lc]);
        }
        __syncthreads();
#pragma unroll
        for (int s = 0; s < 2; ++s) {
            bf16x8 af[2], b1f[4], b2f[4];
#pragma unroll
            for (int m = 0; m < 2; ++m)
                af[m] = *(const bf16x8*)(&As[wave * 32 + m * 16 + fr][s * 32 + fo]);
#pragma unroll
            for (int n = 0; n < 4; ++n) {
                b1f[n] = *(const bf16x8*)(&B1s[n * 16 + fr][s * 32 + fo]);
                b2f[n] = *(const bf16x8*)(&B2s[n * 16 + fr][s * 32 + fo]);
            }
#pragma unroll
            for (int m = 0; m < 2; ++m)
#pragma unroll
                for (int n = 0; n < 4; ++n) {
                    acc1[m][n] = __builtin_amdgcn_mfma_f32_16x16x32_bf16(af[m], b1f[n], acc1[m][n], 0, 0, 0);
                    acc2[m][n] = __builtin_amdgcn_mfma_f32_16x16x32_bf16(af[m], b2f[n], acc2[m][n], 0, 0, 0);
                }
        }
    }
    int fq = (lane >> 4) * 4;
#pragma unroll
    for (int m = 0; m < 2; ++m)
#pragma unroll
        for (int n = 0; n < 4; ++n) {
            int row = m0 + wave * 32 + m * 16 + fq;
            int col = n0 + n * 16 + fr;
            float b1v = (col < HIDv) ? b1[col] : 0.0f;
            float b2v = (col < HIDv) ? b2[col] : 0.0f;
#pragma unroll
            for (int r = 0; r < 4; ++r) {
                float c1 = acc1[m][n][r] + b1v;
                float c2 = acc2[m][n][r] + b2v;
                float sw = c1 * (1.0f + __expf(-c1));
                outH[(long)(row + r) * HIDP + col] = (__bf16)(sw * c2);
            }
        }
}

// ---------------- flash attention (causal), double-buffered + counted vmcnt ----------------
__global__ __launch_bounds__(256) void k_attn(const __bf16* __restrict__ Q,
                                              const __bf16* __restrict__ KR,
                                              const __bf16* __restrict__ VT,
                                              __bf16* __restrict__ O) {
    __shared__ __align__(16) __bf16 Ks[2][64][64];
    __shared__ __align__(16) __bf16 Vs[2][64][64];
    __shared__ __align__(16) __bf16 Ps[4][16][64];
    int tid = threadIdx.x, lane = tid & 63, w = tid >> 6;
    int bh = blockIdx.x >> 5;
    int qt = 31 - (blockIdx.x & 31);
    int q0 = qt * 64;
    int b = bh >> 4, h = bh & 15;
    const long qbase = ((long)b * Tv) * Cv + h * HSv;
    const long kbase = (long)bh * Tv * 64;
    const long vbase = (long)bh * 64 * Tv;
    int fr = lane & 15, fog = lane >> 4;
    int fo = fog * 8, fq = fog * 4;
    int lr = lane >> 3, lc8 = (lane & 7) * 8;
    int qrow = q0 + w * 16 + fr;
    // Q fragments: load, pin, drain (so in-loop vmcnt counting is exact)
    int4 qi0 = *(const int4*)(Q + qbase + (long)qrow * Cv + fo);
    int4 qi1 = *(const int4*)(Q + qbase + (long)qrow * Cv + 32 + fo);
    asm volatile("" :: "v"(qi0.x), "v"(qi0.y), "v"(qi0.z), "v"(qi0.w),
                       "v"(qi1.x), "v"(qi1.y), "v"(qi1.z), "v"(qi1.w));
    bf16x8 qf0 = *(bf16x8*)&qi0;
    bf16x8 qf1 = *(bf16x8*)&qi1;
    asm volatile("s_waitcnt vmcnt(0)" ::: "memory");

    const float SCL = 0.125f * 1.44269504f;  // (1/sqrt(64)) * log2(e)
    f32x4 o[4] = {};
    float mrow[4], lrow[4];
#pragma unroll
    for (int r = 0; r < 4; ++r) { mrow[r] = -INFINITY; lrow[r] = 0.0f; }

    // stage tile j into buffer bufi: 4 vmem ops per lane
    auto stage = [&](int bufi, int j0) {
#pragma unroll
        for (int i = 0; i < 2; ++i) {
            int rk = w * 16 + i * 8 + lr;
            gload_lds16(KR + kbase + (long)(j0 + rk) * 64 + lc8, &Ks[bufi][rk][lc8]);
            gload_lds16(VT + vbase + (long)rk * Tv + j0 + lc8, &Vs[bufi][rk][lc8]);
        }
    };

    stage(0, 0);
    for (int t = 0; t <= qt; ++t) {
        int cur = t & 1;
        if (t < qt) {
            stage(cur ^ 1, (t + 1) * 64);
            asm volatile("s_waitcnt vmcnt(4)" ::: "memory");   // tile t landed; t+1 in flight
        } else {
            asm volatile("s_waitcnt vmcnt(0)" ::: "memory");
        }
        __builtin_amdgcn_s_barrier();                          // all waves' tile-t data visible
        // ---- QK^T ----
        f32x4 s4[4];
#pragma unroll
        for (int kk = 0; kk < 4; ++kk) {
            int key = kk * 16 + fr;
            const char* krow = (const char*)&Ks[cur][key][0];
            bf16x8 kf0 = *(const bf16x8*)(krow + ((fo * 2) ^ ((key & 7) << 4)));
            bf16x8 kf1 = *(const bf16x8*)(krow + ((64 + fo * 2) ^ ((key & 7) << 4)));
            f32x4 z = {};
            z = __builtin_amdgcn_mfma_f32_16x16x32_bf16(qf0, kf0, z, 0, 0, 0);
            z = __builtin_amdgcn_mfma_f32_16x16x32_bf16(qf1, kf1, z, 0, 0, 0);
            s4[kk] = z;
        }
        // ---- softmax (log2 domain) ----
        bool diag = (t == qt);
#pragma unroll
        for (int r = 0; r < 4; ++r) {
#pragma unroll
            for (int kk = 0; kk < 4; ++kk) {
                float v = s4[kk][r] * SCL;
                if (diag) {
                    int key = kk * 16 + fr;
                    int qr = w * 16 + fq + r;
                    if (key > qr) v = -INFINITY;
                }
                s4[kk][r] = v;
            }
            float mx = fmaxf(fmaxf(s4[0][r], s4[1][r]), fmaxf(s4[2][r], s4[3][r]));
#pragma unroll
            for (int msk = 1; msk < 16; msk <<= 1) mx = fmaxf(mx, __shfl_xor(mx, msk));
            float mn = fmaxf(mrow[r], mx);
            float alpha = exp2f(mrow[r] - mn);
            mrow[r] = mn;
            float rs = 0.0f;
#pragma unroll
            for (int kk = 0; kk < 4; ++kk) {
                float pv = exp2f(s4[kk][r] - mn);
                s4[kk][r] = pv;
                rs += pv;
            }
#pragma unroll
            for (int msk = 1; msk < 16; msk <<= 1) rs += __shfl_xor(rs, msk);
            lrow[r] = lrow[r] * alpha + rs;
#pragma unroll
            for (int f = 0; f < 4; ++f) o[f][r] *= alpha;
            char* prow = (char*)&Ps[w][fq + r][0];
#pragma unroll
            for (int kk = 0; kk < 4; ++kk) {
                int colb = ((kk * 16 + fr) * 2) ^ (((fq + r) & 7) << 4);
                *(__bf16*)(prow + colb) = (__bf16)s4[kk][r];
            }
        }
        // ---- PV (per-wave P tile, intra-wave dep only) ----
        const char* prd = (const char*)&Ps[w][fr][0];
        bf16x8 pa0 = *(const bf16x8*)(prd + ((fo * 2) ^ ((fr & 7) << 4)));
        bf16x8 pa1 = *(const bf16x8*)(prd + ((64 + fo * 2) ^ ((fr & 7) << 4)));
#pragma unroll
        for (int f = 0; f < 4; ++f) {
            int vrow = f * 16 + fr;
            const char* vrd = (const char*)&Vs[cur][vrow][0];
            bf16x8 v0 = *(const bf16x8*)(vrd + ((fo * 2) ^ ((vrow & 7) << 4)));
            bf16x8 v1 = *(const bf16x8*)(vrd + ((64 + fo * 2) ^ ((vrow & 7) << 4)));
            o[f] = __builtin_amdgcn_mfma_f32_16x16x32_bf16(pa0, v0, o[f], 0, 0, 0);
            o[f] = __builtin_amdgcn_mfma_f32_16x16x32_bf16(pa1, v1, o[f], 0, 0, 0);
        }
        __builtin_amdgcn_s_barrier();                          // all reads of buf[cur] done
    }
#pragma unroll
    for (int f = 0; f < 4; ++f)
#pragma unroll
        for (int r = 0; r < 4; ++r) {
            int row = q0 + w * 16 + fq + r;
            int col = f * 16 + fr;
            O[qbase + (long)row * Cv + col] = (__bf16)(o[f][r] / lrow[r]);
        }
}

// ---------------- launch ----------------
extern "C" void kernel_launch(void* const* d_in, const int* in_sizes, int n_in,
                              void* d_out, int out_size, void* d_ws, size_t ws_size,
                              hipStream_t stream) {
    const float* x    = (const float*)d_in[0];
    const float* ln1w = (const float*)d_in[1];
    const float* Wq   = (const float*)d_in[2];
    const float* Wk   = (const float*)d_in[3];
    const float* Wv   = (const float*)d_in[4];
    const float* Wo   = (const float*)d_in[5];
    const float* bo   = (const float*)d_in[6];
    const float* w1   = (const float*)d_in[7];
    const float* b1   = (const float*)d_in[8];
    const float* w2   = (const float*)d_in[9];
    const float* b2   = (const float*)d_in[10];
    const float* w3   = (const float*)d_in[11];
    const float* b3   = (const float*)d_in[12];
    const float* ln2w = (const float*)d_in[13];
    const float* cosT = (const float*)d_in[14];
    const float* sinT = (const float*)d_in[15];
    float* out = (float*)d_out;

    char* p = (char*)d_ws;
    auto alloc = [&](size_t bytes) {
        char* r = p;
        p += (bytes + 255) & ~(size_t)255;
        return r;
    };
    float*  x1f = (float*)alloc((size_t)Mv * Cv * 4);
    __bf16* qh  = (__bf16*)alloc((size_t)Mv * Cv * 2);
    __bf16* kh  = (__bf16*)alloc((size_t)Mv * Cv * 2);
    __bf16* vh  = (__bf16*)alloc((size_t)Mv * Cv * 2);
    __bf16* ah  = (__bf16*)alloc((size_t)Mv * Cv * 2);
    float*  x3f = (float*)alloc((size_t)Mv * Cv * 4);
    __bf16* x1h = (__bf16*)alloc((size_t)Mv * Cv * 2);
    __bf16* VT  = (__bf16*)x1h;                                   // alias: x1h dead after QKV GEMM
    __bf16* x3h = (__bf16*)alloc((size_t)Mv * Cv * 2);
    __bf16* KR  = (__bf16*)alloc((size_t)Bv * Hv * Tv * HSv * 2); // 8 MB (fixed size)
    __bf16* hh  = (__bf16*)alloc((size_t)Mv * HIDP * 2);
    __bf16* wqkvh = (__bf16*)alloc((size_t)3072 * Cv * 2);
    __bf16* woh = (__bf16*)alloc((size_t)Cv * Cv * 2);
    __bf16* w1h = (__bf16*)alloc((size_t)HIDP * Cv * 2);
    __bf16* w2h = (__bf16*)alloc((size_t)HIDP * Cv * 2);
    __bf16* w3h = (__bf16*)alloc((size_t)Cv * HIDP * 2);

    const long nCC = (long)Cv * Cv;
    CastArgs ca;
    ca.seg[0] = {Wq, wqkvh,           nCC, nCC, 0, 0};
    ca.seg[1] = {Wk, wqkvh + nCC,     nCC, nCC, 0, 0};
    ca.seg[2] = {Wv, wqkvh + 2 * nCC, nCC, nCC, 0, 0};
    ca.seg[3] = {Wo, woh,             nCC, nCC, 0, 0};
    ca.seg[4] = {w1, w1h, (long)HIDv * Cv, (long)HIDP * Cv, 0, 0};
    ca.seg[5] = {w2, w2h, (long)HIDv * Cv, (long)HIDP * Cv, 0, 0};
    ca.seg[6] = {w3, w3h, (long)Cv * HIDv, (long)Cv * HIDP, HIDv, HIDP};
    k_castall<<<2048, 256, 0, stream>>>(ca);

    k_rmsnorm<<<Mv, 256, 0, stream>>>(x, ln1w, x1f, x1h);

    // fused QKV GEMM: N = 3072
    k_gemm<128, 4><<<dim3(24, 32), 256, 0, stream>>>(x1h, wqkvh, Mv, 3072, Cv,
        nullptr, nullptr, nullptr, qh, kh, vh);

    k_rope<<<(Mv * 512 + 255) / 256, 256, 0, stream>>>(qh, kh, KR, cosT, sinT);
    k_vtrans<<<dim3(Tv / 64, Bv * Hv), 256, 0, stream>>>(vh, VT);

    k_attn<<<1024, 256, 0, stream>>>(qh, KR, VT, ah);

    // x2 = x1 + attn @ Wo^T + bo  (into x1f)
    k_gemm<64, 1><<<dim3(8, 64), 256, 0, stream>>>(ah, woh, Mv, Cv, Cv,
        x1f, bo, x1f, nullptr, nullptr, nullptr);

    k_rmsnorm<<<Mv, 256, 0, stream>>>(x1f, ln2w, x3f, x3h);

    // h = swish_bug(x3@w1^T + b1) * (x3@w2^T + b2)  (fused, bf16 out, no h1 round-trip)
    k_ffn<<<dim3(HIDP / 64, 32), 256, 0, stream>>>(x3h, w1h, w2h, b1, b2, hh);

    // out = x3 + h @ w3^T + b3
    k_gemm<64, 1><<<dim3(8, 64), 256, 0, stream>>>(hh, w3h, Mv, Cv, HIDP,
        out, b3, x3f, nullptr, nullptr, nullptr);
}